// Round 8
// baseline (121547.925 us; speedup 1.0000x reference)
//
#include <hip/hip_runtime.h>

#define T_STEPS 16384
#define N 2048
#define NBLK 256          // one block per CU (r3-proven skeleton)
#define THREADS 256
#define NSLOT 4           // g ring slots; blocks stay within 1 step

typedef float f32x4 __attribute__((ext_vector_type(4)));

// ---------------------------------------------------------------------------
// Parity-slot protocol (evolves proven r3/r4/r6 slot ring):
//   g in [0,1] always => sign bit free. Publish p ("g entering step p") goes
//   to slot p&3 as   bits(g) | S(p)<<31,  S(p) = (p>>2)&1  (flips each ring
//   revolution; previous occupant p-4 has opposite S => distinguishable).
//   EVERY DWORD SELF-VALIDATES => consumers may use wide dwordx4 loads: the
//   fabric currency is coherent REQUESTS (r3: 650K scalar req/step = 2.5us;
//   r4: ~1.5M = 3.55us), so 16B loads cut requests 4x (131K/step first sweep).
//   Consumer loads: inline-asm global_load_dwordx4 sc0 sc1 nt (bypass L1 and
//   the non-coherent per-XCD L2). Producer stores: proven intrinsic
//   agent-scope scalar atomics (2048 req/step, negligible).
//   0xAA poison has sign=1 == stale for steps 0..3 (expect S=0). Ring-reuse
//   safety: publish p+4 starts only after poll(p+3) succeeded everywhere =>
//   all readers of slot p&3 are long done.
// ---------------------------------------------------------------------------

__global__ void __launch_bounds__(THREADS, 1)
lif_kernel(const float* __restrict__ x_in, const float* __restrict__ w,
           const float* __restrict__ E_L, const float* __restrict__ tau_m,
           const float* __restrict__ R_I, const float* __restrict__ tau_g,
           const float* __restrict__ v0,  const float* __restrict__ g0,
           float* __restrict__ out, unsigned* __restrict__ slots)
{
    __shared__ float w_lds[8][N];     // 64 KB: this block's 8 w-columns
    __shared__ float g_lds[2][N];     // 16 KB: double-buffered g image

    const int tid = threadIdx.x;
    const int blk = blockIdx.x;
    const int j0  = blk * 8;

    // ---- one-time: stage w columns (transposed, diag=0) -- r3 verbatim ----
    for (int r8 = 0; r8 < 8; ++r8) {
        int i = r8 * THREADS + tid;
        const float4* wrow = reinterpret_cast<const float4*>(w + (size_t)i * N + j0);
        float4 a4 = wrow[0], b4 = wrow[1];
        float vals[8] = {a4.x, a4.y, a4.z, a4.w, b4.x, b4.y, b4.z, b4.w};
        #pragma unroll
        for (int jc = 0; jc < 8; ++jc)
            w_lds[jc][i] = (i == j0 + jc) ? 0.0f : vals[jc];
    }
    __syncthreads();

    // 32-lane group per output column (r3-proven mapping)
    const int col = tid >> 5;   // 0..7
    const int s   = tid & 31;   // lane in group
    const int j   = j0 + col;

    // persistent neuron state in owner-lane (s==0) registers
    float v_st = 0.f, g_st = 0.f, eL = 0.f, tm = 1.f, ri = 0.f, tg = 1.f, xv = 0.f;
    if (s == 0) {
        v_st = v0[j]; g_st = g0[j];
        eL = E_L[j]; tm = tau_m[j]; ri = R_I[j]; tg = tau_g[j];
        xv = x_in[j];
        // publish 0: slot 0, S(0)=0 -> plain bits (g>=0 so sign already 0)
        __hip_atomic_store(&slots[j], __float_as_uint(g_st),
                           __ATOMIC_RELAXED, __HIP_MEMORY_SCOPE_AGENT);
    }

    for (int t = 0; t < T_STEPS; ++t) {
        const unsigned* slot = slots + (size_t)(t & 3) * N;
        const unsigned  es   = (((unsigned)t >> 2) & 1u) << 31;   // expected sign

        // ---- poll own 8 dwords (2 x dwordx4, coherent-bypass); every dword
        //      self-validates via sign bit. Load latency is the backoff. ----
        const unsigned* p = slot + tid * 8;
        f32x4 a, b;
        for (;;) {
            asm volatile(
                "global_load_dwordx4 %0, %2, off sc0 sc1 nt\n\t"
                "global_load_dwordx4 %1, %2, off offset:16 sc0 sc1 nt\n\t"
                "s_waitcnt vmcnt(0)"
                : "=&v"(a), "=&v"(b)
                : "v"(p)
                : "memory");
            unsigned mm = (__float_as_uint(a[0]) ^ es) | (__float_as_uint(a[1]) ^ es)
                        | (__float_as_uint(a[2]) ^ es) | (__float_as_uint(a[3]) ^ es)
                        | (__float_as_uint(b[0]) ^ es) | (__float_as_uint(b[1]) ^ es)
                        | (__float_as_uint(b[2]) ^ es) | (__float_as_uint(b[3]) ^ es);
            if (!(mm & 0x80000000u)) break;   // per-lane exit; exec-mask handles rest
        }

        // ---- decode (clear sign) and share via LDS; contiguous b128 writes ----
        float* gl = g_lds[t & 1];
        f32x4 ca, cb;
        #pragma unroll
        for (int c = 0; c < 4; ++c) {
            ca[c] = __uint_as_float(__float_as_uint(a[c]) & 0x7FFFFFFFu);
            cb[c] = __uint_as_float(__float_as_uint(b[c]) & 0x7FFFFFFFu);
        }
        *reinterpret_cast<f32x4*>(&gl[tid * 8])     = ca;
        *reinterpret_cast<f32x4*>(&gl[tid * 8 + 4]) = cb;
        __syncthreads();

        // ---- matvec: r3-proven. 32-lane group, float4 over rows ----
        float4 acc = {0.f, 0.f, 0.f, 0.f};
        #pragma unroll
        for (int k = 0; k < 16; ++k) {
            int r = s * 4 + k * 128;
            float4 g4 = *reinterpret_cast<const float4*>(&gl[r]);
            float4 w4 = *reinterpret_cast<const float4*>(&w_lds[col][r]);
            acc.x = fmaf(w4.x, g4.x, acc.x);
            acc.y = fmaf(w4.y, g4.y, acc.y);
            acc.z = fmaf(w4.z, g4.z, acc.z);
            acc.w = fmaf(w4.w, g4.w, acc.w);
        }
        float sum = (acc.x + acc.y) + (acc.z + acc.w);
        #pragma unroll
        for (int m = 16; m >= 1; m >>= 1)
            sum += __shfl_xor(sum, m, 64);   // masks <=16 stay in 32-lane group

        // ---- neuron update + publish (owner lane; publish FIRST) ----
        if (s == 0) {
            float I      = fmaf(0.9f, xv, sum);
            float v_next = v_st + (eL - v_st + I * ri) / tm;
            float soft   = 1.0f / (1.0f + expf(30.0f - v_next)); // sigmoid(v-30)
            bool  spiked = v_next >= 30.0f;
            v_st = spiked ? eL : v_next;
            g_st = spiked ? 1.0f : (g_st - g_st / tg);
            unsigned Sn  = (((unsigned)(t + 1) >> 2) & 1u) << 31;
            __hip_atomic_store(&slots[(size_t)((t + 1) & 3) * N + j],
                               __float_as_uint(g_st) | Sn,
                               __ATOMIC_RELAXED, __HIP_MEMORY_SCOPE_AGENT);
            out[(size_t)t * N + j] = soft;                   // off critical path
            if (t + 1 < T_STEPS) xv = x_in[(size_t)(t + 1) * N + j];
        }
        // no trailing barrier: step t+1 writes the OTHER g_lds buffer; a wave
        // re-enters this buffer only after the t+1 __syncthreads, which needs
        // every wave to have finished its step-t matvec reads (program order).
    }
}

extern "C" void kernel_launch(void* const* d_in, const int* in_sizes, int n_in,
                              void* d_out, int out_size, void* d_ws, size_t ws_size,
                              hipStream_t stream) {
    const float* x_in  = (const float*)d_in[0];
    const float* w     = (const float*)d_in[1];
    const float* E_L   = (const float*)d_in[2];
    const float* tau_m = (const float*)d_in[3];
    const float* R_I   = (const float*)d_in[4];
    const float* tau_g = (const float*)d_in[5];
    const float* v0    = (const float*)d_in[6];
    const float* g0    = (const float*)d_in[7];
    float* out = (float*)d_out;

    unsigned* slots = (unsigned*)d_ws;   // 4 slots x 2048 x 4B = 32 KB

    // 0xAA pattern = sign bit 1 = "stale" for the first ring revolution.
    // Harness re-poisons d_ws each timed call; we poison ourselves too so the
    // very first (correctness) call is covered regardless of initial contents.
    hipMemsetAsync(d_ws, 0xAA, NSLOT * N * sizeof(unsigned), stream);

    void* args[] = {(void*)&x_in, (void*)&w, (void*)&E_L, (void*)&tau_m,
                    (void*)&R_I, (void*)&tau_g, (void*)&v0, (void*)&g0,
                    (void*)&out, (void*)&slots};
    hipLaunchCooperativeKernel((const void*)lif_kernel, dim3(NBLK), dim3(THREADS),
                               args, 0, stream);
}